// Round 5
// baseline (811.070 us; speedup 1.0000x reference)
//
#include <hip/hip_runtime.h>

// ---------------------------------------------------------------------------
// OmegaPLM block, MI355X (gfx950). Inputs AND output are FLOAT32.
// R7 (872us): split-K stores; res_ln_fuse; merged V-transpose.
// R9 (793us): GEMM BK=64 + both-sides XOR swizzle (u^=row&7 @16B units);
// RoPE trig table.
// R10: serial-overhead bundle — (a) all 8 weight transposes hoisted to 2
// batched preamble dispatches (grid.z=4); (b) copy_f32 removed (layer-0
// readers take node_in directly via resid param); (c) XCD-aware bijective
// block swizzle in gemm_bt (y-fastest column bands -> B-strips L2-resident).
// GEMM inner loop unchanged from R9.
// ---------------------------------------------------------------------------

typedef __bf16 bf16;
typedef __attribute__((ext_vector_type(8))) __bf16 bf16x8;
typedef __attribute__((ext_vector_type(4))) float f32x4;

#define NODE_D 1280
#define PROJ_D 2560
#define ATTN_D 256
#define HDIM 5376     // 2*PROJ + ATTN
#define LSEQ 1024
#define NTOK 2048     // B*L

__device__ __forceinline__ void async_ld16(const void* gsrc, void* ldst) {
  __builtin_amdgcn_global_load_lds(
      (__attribute__((address_space(1))) void*)gsrc,
      (__attribute__((address_space(3))) void*)ldst, 16, 0, 0);
}

__device__ __forceinline__ float sigmoidf_fast(float x) {
  return 1.f / (1.f + __expf(-x));
}

// ---------------------------------------------------------------------------
// GEMM: C[M,N] = A[M,K] * Bt[N,K]^T, bf16 inputs, fp32 accumulate.
// 128x128 tile, BK=64, 4 waves, 4x4 grid of 16x16x32 MFMAs per wave.
// LDS swizzle: physical unit = nominal unit ^ (row&7) (16B units), applied
// on the global source (global_load_lds writes linearly) AND the ds_read.
// Block swizzle: y-fastest logical ids chunked per XCD (bijective, n%8==0).
// MODE 0: h = silu(acc + b_gva_f32[col])                    -> bf16 C
// MODE 1: S = acc + bias_f32[col] + rel_f32[clip(row-col)]  -> f32 C
// MODE 2: po = acc * gates_bf16[row,col]                    -> bf16 C
// MODE 4: plain f32 partial store (split-K, reduced later)  -> f32 C
// ---------------------------------------------------------------------------
template <int MODE>
__global__ __launch_bounds__(256, 3) void gemm_bt(
    const bf16* __restrict__ A, const bf16* __restrict__ Bt, int K,
    int lda, int ldb, void* __restrict__ C, int ldc,
    const void* __restrict__ E0, const void* __restrict__ E1,
    long zA, long zB, long zCb, long zE0b) {
  __shared__ __align__(16) bf16 As[128 * 64];
  __shared__ __align__(16) bf16 Bs[128 * 64];

  const int z = blockIdx.z;
  A += (size_t)zA * z;
  Bt += (size_t)zB * z;
  char* Cb = (char*)C + (size_t)zCb * z;
  const char* e0 = (const char*)E0 + (size_t)zE0b * z;

  // XCD-aware bijective swizzle (per z-slice; slice size is a multiple of 8
  // at every call site, so the round-robin phase is consistent).
  int bx = blockIdx.x, by = blockIdx.y;
  {
    const int gx = gridDim.x, gy = gridDim.y;
    const int n = gx * gy;
    if ((n & 7) == 0) {
      const int cpx = n >> 3;
      const int p = by * gx + bx;              // physical dispatch order
      const int lg = (p & 7) * cpx + (p >> 3); // logical tile (y-fastest)
      bx = lg / gy;
      by = lg % gy;
    }
  }

  const int rowBase = by * 128;
  const int colBase = bx * 128;
  const int tid = threadIdx.x;
  const int lane = tid & 63;
  const int wv = tid >> 6;
  const int wrow = (wv >> 1) * 64;
  const int wcol = (wv & 1) * 64;
  const int fm = lane & 15;
  const int fq = lane >> 4;

  const bf16* Ablk = A + (size_t)rowBase * lda;
  const bf16* Bblk = Bt + (size_t)colBase * ldb;

  f32x4 zero = {0.f, 0.f, 0.f, 0.f};
  f32x4 acc[4][4];
#pragma unroll
  for (int i = 0; i < 4; i++)
#pragma unroll
    for (int j = 0; j < 4; j++) acc[i][j] = zero;

  for (int k0 = 0; k0 < K; k0 += 64) {
    __syncthreads();
#pragma unroll
    for (int i = 0; i < 4; i++) {
      const int slot = tid + i * 256;          // this thread's 16B slot
      const int row = slot >> 3;               // tile-local row 0..127
      const int u = (slot & 7) ^ (row & 7);    // swizzled source unit
      bf16* dA = As + ((i * 256 + wv * 64) << 3);  // wave-uniform LDS base
      bf16* dB = Bs + ((i * 256 + wv * 64) << 3);
      async_ld16(Ablk + (size_t)row * lda + k0 + (u << 3), dA);
      async_ld16(Bblk + (size_t)row * ldb + k0 + (u << 3), dB);
    }
    __syncthreads();

#pragma unroll
    for (int s = 0; s < 2; s++) {
      bf16x8 aF[4], bF[4];
#pragma unroll
      for (int i = 0; i < 4; i++) {
        const int r = wrow + i * 16 + fm;
        aF[i] = *(const bf16x8*)(As + r * 64 +
                                 ((((s << 2) | fq) ^ (r & 7)) << 3));
      }
#pragma unroll
      for (int j = 0; j < 4; j++) {
        const int r = wcol + j * 16 + fm;
        bF[j] = *(const bf16x8*)(Bs + r * 64 +
                                 ((((s << 2) | fq) ^ (r & 7)) << 3));
      }
#pragma unroll
      for (int i = 0; i < 4; i++)
#pragma unroll
        for (int j = 0; j < 4; j++)
          acc[i][j] = __builtin_amdgcn_mfma_f32_16x16x32_bf16(
              aF[i], bF[j], acc[i][j], 0, 0, 0);
    }
  }

  // epilogue: C/D layout col=lane&15, row=quad*4+reg
#pragma unroll
  for (int i = 0; i < 4; i++) {
#pragma unroll
    for (int t = 0; t < 4; t++) {
      const int r = rowBase + wrow + i * 16 + fq * 4 + t;
#pragma unroll
      for (int j = 0; j < 4; j++) {
        const int cc = colBase + wcol + j * 16 + fm;
        float v = acc[i][j][t];
        if constexpr (MODE == 0) {
          v += ((const float*)e0)[cc];
          v = v * sigmoidf_fast(v);
          ((bf16*)Cb)[(size_t)r * ldc + cc] = (bf16)v;
        } else if constexpr (MODE == 1) {
          v += ((const float*)e0)[cc];
          int d = r - cc;
          d = d < -64 ? -64 : (d > 64 ? 64 : d);
          v += ((const float*)E1)[d + 64];
          ((float*)Cb)[(size_t)r * ldc + cc] = v;
        } else if constexpr (MODE == 2) {
          float gt = (float)((const bf16*)e0)[(size_t)r * HDIM + cc];
          ((bf16*)Cb)[(size_t)r * ldc + cc] = (bf16)(v * gt);
        } else {  // MODE 4: split-K partial, plain store
          ((float*)Cb)[(size_t)r * ldc + cc] = v;
        }
      }
    }
  }
}

// ---------------------------------------------------------------------------
// transpose f32 weight -> bf16: out[c][r] = (bf16)in[r][c]. 64x64 tiles.
// z-batched over layers via grid.z.
// ---------------------------------------------------------------------------
__global__ void transpose_f2b(const float* __restrict__ in0,
                              bf16* __restrict__ out0, int ldin, int ldout,
                              long zIn, long zOut) {
  __shared__ __align__(16) bf16 t[64][72];
  const float* in = in0 + (size_t)zIn * blockIdx.z;
  bf16* out = out0 + (size_t)zOut * blockIdx.z;
  const int rb = blockIdx.y * 64, cb = blockIdx.x * 64;
  const int tx = threadIdx.x & 7, ty = threadIdx.x >> 3;
#pragma unroll
  for (int rr = 0; rr < 64; rr += 32) {
    const int r = ty + rr;
    const float4* p = (const float4*)&in[(size_t)(rb + r) * ldin + cb + tx * 8];
    float4 a = p[0], b = p[1];
    t[tx * 8 + 0][r] = (bf16)a.x; t[tx * 8 + 1][r] = (bf16)a.y;
    t[tx * 8 + 2][r] = (bf16)a.z; t[tx * 8 + 3][r] = (bf16)a.w;
    t[tx * 8 + 4][r] = (bf16)b.x; t[tx * 8 + 5][r] = (bf16)b.y;
    t[tx * 8 + 6][r] = (bf16)b.z; t[tx * 8 + 7][r] = (bf16)b.w;
  }
  __syncthreads();
#pragma unroll
  for (int rr = 0; rr < 64; rr += 32) {
    const int c = ty + rr;
    *(bf16x8*)&out[(size_t)(cb + c) * ldout + rb + tx * 8] =
        *(const bf16x8*)&t[c][tx * 8];
  }
}

// internal bf16 transpose — V slices of h; z-batched via grid.z
__global__ void transpose_int(const bf16* __restrict__ in0, bf16* __restrict__ out0,
                              int ldin, int ldout, long zIn, long zOut) {
  __shared__ __align__(16) bf16 t[64][72];
  const bf16* in = in0 + (size_t)zIn * blockIdx.z;
  bf16* out = out0 + (size_t)zOut * blockIdx.z;
  const int rb = blockIdx.y * 64, cb = blockIdx.x * 64;
  const int tx = threadIdx.x & 7, ty = threadIdx.x >> 3;
#pragma unroll
  for (int rr = 0; rr < 64; rr += 32) {
    const int r = ty + rr;
    bf16x8 v = *(const bf16x8*)&in[(size_t)(rb + r) * ldin + cb + tx * 8];
#pragma unroll
    for (int e = 0; e < 8; e++) t[tx * 8 + e][r] = v[e];
  }
  __syncthreads();
#pragma unroll
  for (int rr = 0; rr < 64; rr += 32) {
    const int c = ty + rr;
    *(bf16x8*)&out[(size_t)(cb + c) * ldout + rb + tx * 8] =
        *(const bf16x8*)&t[c][tx * 8];
  }
}

// ---------------------------------------------------------------------------
// adaLN: gba[l][b][:] = silu(cond[b]) @ w_adaln[l] + b_adaln[l]
// ---------------------------------------------------------------------------
__global__ void gba_init(const float* __restrict__ b_adaln,
                         float* __restrict__ gba) {
  const int i = blockIdx.x * 256 + threadIdx.x;  // over 4*2*3840
  if (i < 4 * 2 * 3840) {
    const int l = i / (2 * 3840);
    const int c = i % 3840;
    gba[i] = b_adaln[l * 3840 + c];
  }
}

// grid (30, 4, 8), 256 thr = 128 cols x 2 k-subgroups; k chunk = 160 per z.
__global__ void adaln_part(const float* __restrict__ cond,
                           const float* __restrict__ w_adaln,
                           float* __restrict__ gba) {
  __shared__ float sc[2 * NODE_D];
  __shared__ float red[2][2][128];
  const int l = blockIdx.y, z = blockIdx.z;
  const int cl = threadIdx.x & 127;
  const int col = blockIdx.x * 128 + cl;
  const int kg = threadIdx.x >> 7;
  for (int i = threadIdx.x; i < 2 * NODE_D; i += 256) {
    float v = cond[i];
    sc[i] = v * sigmoidf_fast(v);
  }
  __syncthreads();
  const float* w = w_adaln + (size_t)l * NODE_D * 3840;
  const int k0 = z * 160 + kg * 80;
  float a0 = 0.f, a1 = 0.f;
  for (int k = k0; k < k0 + 80; k++) {
    float wv = w[(size_t)k * 3840 + col];
    a0 += sc[k] * wv;
    a1 += sc[NODE_D + k] * wv;
  }
  red[kg][0][cl] = a0;
  red[kg][1][cl] = a1;
  __syncthreads();
  if (kg == 0) {
    a0 += red[1][0][cl];
    a1 += red[1][1][cl];
    atomicAdd(&gba[(size_t)(l * 2 + 0) * 3840 + col], a0);
    atomicAdd(&gba[(size_t)(l * 2 + 1) * 3840 + col], a1);
  }
}

// xmod = LN(x) * (1+gamma) + beta, bf16 out. grid=2048, 256 thr. (layer 0)
__global__ void ln_mod_kernel(const float* __restrict__ xin,
                              const float* __restrict__ gba_l,
                              bf16* __restrict__ xmod) {
  __shared__ float red[2][4];
  const int row = blockIdx.x, b = row >> 10, tt = threadIdx.x;
  const float* x = xin + (size_t)row * NODE_D;
  float vals[5], s = 0.f, s2 = 0.f;
#pragma unroll
  for (int i = 0; i < 5; i++) {
    float v = x[tt + i * 256];
    vals[i] = v; s += v; s2 += v * v;
  }
#pragma unroll
  for (int off = 32; off >= 1; off >>= 1) {
    s += __shfl_down(s, off, 64);
    s2 += __shfl_down(s2, off, 64);
  }
  const int wv = tt >> 6, lane = tt & 63;
  if (lane == 0) { red[0][wv] = s; red[1][wv] = s2; }
  __syncthreads();
  s = red[0][0] + red[0][1] + red[0][2] + red[0][3];
  s2 = red[1][0] + red[1][1] + red[1][2] + red[1][3];
  const float mean = s * (1.f / NODE_D);
  const float var = s2 * (1.f / NODE_D) - mean * mean;
  const float inv = rsqrtf(var + 1e-5f);
  const float* gm = gba_l + b * 3840;
#pragma unroll
  for (int i = 0; i < 5; i++) {
    const int c = tt + i * 256;
    float v = (vals[i] - mean) * inv * (1.f + gm[c]) + gm[NODE_D + c];
    xmod[(size_t)row * NODE_D + c] = (bf16)v;
  }
}

// ---------------------------------------------------------------------------
// res_ln_fuse: node_new = resid + (p0+p1+b_out)*(1+alpha);
//   LAST=0: nodef <- node_new; xmod <- LN(node_new)*(1+gamma_next)+beta_next
//   LAST=1: outNode <- node_new (no LN needed)
// resid = node_in for layer 0, nodef otherwise. grid=2048, 256 thr x 5.
// ---------------------------------------------------------------------------
template <bool LAST>
__global__ void res_ln_fuse(const float* __restrict__ p0,
                            const float* __restrict__ p1,
                            const float* __restrict__ b_out_l,
                            const float* __restrict__ gba_l,     // alpha at +2560
                            const float* __restrict__ gba_next,  // gamma/beta
                            const float* __restrict__ resid,
                            float* __restrict__ nodef,
                            bf16* __restrict__ xmod,
                            float* __restrict__ outNode) {
  __shared__ float red[2][4];
  const int row = blockIdx.x, b = row >> 10, tt = threadIdx.x;
  const float* a0 = p0 + (size_t)row * NODE_D;
  const float* a1 = p1 + (size_t)row * NODE_D;
  const float* rs = resid + (size_t)row * NODE_D;
  const float* al = gba_l + b * 3840 + 2560;
  float vals[5], s = 0.f, s2 = 0.f;
#pragma unroll
  for (int i = 0; i < 5; i++) {
    const int c = tt + i * 256;
    float delta = (a0[c] + a1[c] + b_out_l[c]) * (1.f + al[c]);
    float v = rs[c] + delta;
    if (LAST) {
      outNode[(size_t)row * NODE_D + c] = v;
    } else {
      nodef[(size_t)row * NODE_D + c] = v;
    }
    vals[i] = v; s += v; s2 += v * v;
  }
  if (!LAST) {
#pragma unroll
    for (int off = 32; off >= 1; off >>= 1) {
      s += __shfl_down(s, off, 64);
      s2 += __shfl_down(s2, off, 64);
    }
    const int wv = tt >> 6, lane = tt & 63;
    if (lane == 0) { red[0][wv] = s; red[1][wv] = s2; }
    __syncthreads();
    s = red[0][0] + red[0][1] + red[0][2] + red[0][3];
    s2 = red[1][0] + red[1][1] + red[1][2] + red[1][3];
    const float mean = s * (1.f / NODE_D);
    const float var = s2 * (1.f / NODE_D) - mean * mean;
    const float inv = rsqrtf(var + 1e-5f);
    const float* gm = gba_next + b * 3840;
#pragma unroll
    for (int i = 0; i < 5; i++) {
      const int c = tt + i * 256;
      float v = (vals[i] - mean) * inv * (1.f + gm[c]) + gm[NODE_D + c];
      xmod[(size_t)row * NODE_D + c] = (bf16)v;
    }
  }
}

// precompute RoPE table: tab[pos][j] = (cos, sin)(pos * 10000^(-j/128))
__global__ void trig_init(float* __restrict__ tab) {
  const int pos = blockIdx.x;   // 1024
  const int j = threadIdx.x;    // 128
  const float freq = __expf(-(float)j * 0.07195578415606392f);
  const float ang = (float)pos * freq;
  tab[(pos * 128 + j) * 2 + 0] = cosf(ang);
  tab[(pos * 128 + j) * 2 + 1] = sinf(ang);
}

// q,k from h base slice: modulate by mhs (f32), rope (table), fold qk_scaling.
__global__ void qk_rope_kernel(const bf16* __restrict__ h,
                               const float* __restrict__ mhs_w,
                               const float* __restrict__ mhs_b,
                               const float* __restrict__ qk_sc,
                               const float* __restrict__ trig,
                               bf16* __restrict__ q, bf16* __restrict__ k) {
  const int tok = blockIdx.x;
  const int pos = tok & (LSEQ - 1);
  const int d = threadIdx.x;
  const bf16* base = h + (size_t)tok * HDIM + 2 * PROJ_D;
  const int j = d & 127;
  const float2 cssn = ((const float2*)trig)[pos * 128 + j];
  const float cs = cssn.x, sn = cssn.y;
  const float bd = (float)base[d];
  const int pd = (d < 128) ? d + 128 : d - 128;
  const float bp = (float)base[pd];
  const float sgn = (d < 128) ? -1.f : 1.f;

  float v = bd * mhs_w[d] + mhs_b[d];
  float vp = bp * mhs_w[pd] + mhs_b[pd];
  float r0 = v * cs + sgn * vp * sn;
  q[(size_t)tok * ATTN_D + d] = (bf16)(r0 * qk_sc[tok]);

  float v1 = bd * mhs_w[ATTN_D + d] + mhs_b[ATTN_D + d];
  float v1p = bp * mhs_w[ATTN_D + pd] + mhs_b[ATTN_D + pd];
  float r1 = v1 * cs + sgn * v1p * sn;
  k[(size_t)tok * ATTN_D + d] = (bf16)r1;
}

// row softmax: S (f32, 1024 cols) -> P (bf16). grid=2048, 256 thr x 4 elems.
__global__ void softmax_kernel(const float* __restrict__ S, bf16* __restrict__ P) {
  __shared__ float red[8];
  const size_t row = blockIdx.x;
  const float* s = S + row * LSEQ;
  const int tt = threadIdx.x, wv = tt >> 6, lane = tt & 63;
  float v[4];
  float m = -1e30f;
#pragma unroll
  for (int i = 0; i < 4; i++) {
    v[i] = s[tt + i * 256];
    m = fmaxf(m, v[i]);
  }
#pragma unroll
  for (int off = 32; off >= 1; off >>= 1) m = fmaxf(m, __shfl_down(m, off, 64));
  if (lane == 0) red[wv] = m;
  __syncthreads();
  m = fmaxf(fmaxf(red[0], red[1]), fmaxf(red[2], red[3]));
  float sum = 0.f;
#pragma unroll
  for (int i = 0; i < 4; i++) {
    v[i] = __expf(v[i] - m);
    sum += v[i];
  }
#pragma unroll
  for (int off = 32; off >= 1; off >>= 1) sum += __shfl_down(sum, off, 64);
  __syncthreads();
  if (lane == 0) red[4 + wv] = sum;
  __syncthreads();
  const float inv = 1.f / (red[4] + red[5] + red[6] + red[7]);
  bf16* p = P + row * LSEQ;
#pragma unroll
  for (int i = 0; i < 4; i++) p[tt + i * 256] = (bf16)(v[i] * inv);
}

// edge = sum over batch of attn (last layer), f32 out
__global__ void edge_kernel(const bf16* __restrict__ P, float* __restrict__ out) {
  const int idx = (blockIdx.x * 256 + threadIdx.x) * 4;
#pragma unroll
  for (int i = 0; i < 4; i++)
    out[idx + i] = (float)P[idx + i] + (float)P[1048576 + idx + i];
}

// ---------------------------------------------------------------------------
extern "C" void kernel_launch(void* const* d_in, const int* in_sizes, int n_in,
                              void* d_out, int out_size, void* d_ws, size_t ws_size,
                              hipStream_t stream) {
  const float* node_in = (const float*)d_in[0];
  const float* qk_sc   = (const float*)d_in[1];
  const float* bias    = (const float*)d_in[2];
  const float* cond    = (const float*)d_in[3];
  const float* w_gva   = (const float*)d_in[4];
  const float* b_gva   = (const float*)d_in[5];
  const float* mhs_w   = (const float*)d_in[6];
  const float* mhs_b   = (const float*)d_in[7];
  const float* relpos  = (const float*)d_in[8];
  const float* w_out   = (const float*)d_in[9];
  const float* b_out   = (const float*)d_in[10];
  const float* w_adaln = (const float*)d_in[11];
  const float* b_adaln = (const float*)d_in[12];
  (void)in_sizes; (void)n_in; (void)out_size; (void)ws_size;

  char* wsp = (char*)d_ws;
  auto alloc = [&](size_t bytes) {
    char* p = wsp;
    wsp += (bytes + 255) & ~(size_t)255;
    return p;
  };
  float* nodef = (float*)alloc((size_t)NTOK * NODE_D * 4);   // fp32 residual
  float* gba   = (float*)alloc((size_t)8 * 3840 * 4);
  bf16* xmod   = (bf16*)alloc((size_t)NTOK * NODE_D * 2);
  bf16* h      = (bf16*)alloc((size_t)NTOK * HDIM * 2);
  bf16* q      = (bf16*)alloc((size_t)NTOK * ATTN_D * 2);
  bf16* kk     = (bf16*)alloc((size_t)NTOK * ATTN_D * 2);
  bf16* Vt     = (bf16*)alloc((size_t)2 * PROJ_D * LSEQ * 2);
  bf16* wTg    = (bf16*)alloc((size_t)4 * HDIM * NODE_D * 2);   // GVA weights^T
  bf16* wTo    = (bf16*)alloc((size_t)4 * NODE_D * PROJ_D * 2); // OUT weights^T
  float* S     = (float*)alloc((size_t)2 * LSEQ * LSEQ * 4);
  bf16* P      = (bf16*)alloc((size_t)2 * LSEQ * LSEQ * 2);
  bf16* po     = (bf16*)alloc((size_t)NTOK * PROJ_D * 2);
  float* Pp    = (float*)alloc((size_t)2 * NTOK * NODE_D * 4);  // split-K partials
  float* trig  = (float*)alloc((size_t)LSEQ * 128 * 2 * 4);     // RoPE table

  float* outNode = (float*)d_out;
  float* outEdge = outNode + (size_t)NTOK * NODE_D;

  // ---- preamble: tables, adaLN, layer-0 LN, all weight transposes ----
  trig_init<<<1024, 128, 0, stream>>>(trig);
  gba_init<<<120, 256, 0, stream>>>(b_adaln, gba);
  adaln_part<<<dim3(30, 4, 8), 256, 0, stream>>>(cond, w_adaln, gba);
  ln_mod_kernel<<<2048, 256, 0, stream>>>(node_in, gba, xmod);
  // w_gva (4 x 1280 x 5376 f32) -> wTg (4 x 5376 x 1280 bf16)
  transpose_f2b<<<dim3(84, 20, 4), 256, 0, stream>>>(
      w_gva, wTg, HDIM, NODE_D, (long)NODE_D * HDIM, (long)HDIM * NODE_D);
  // w_out (4 x 2560 x 1280 f32) -> wTo (4 x 1280 x 2560 bf16)
  transpose_f2b<<<dim3(20, 40, 4), 256, 0, stream>>>(
      w_out, wTo, NODE_D, PROJ_D, (long)PROJ_D * NODE_D, (long)NODE_D * PROJ_D);

  for (int l = 0; l < 4; ++l) {
    // h = silu(xmod @ w_gva + b_gva)
    gemm_bt<0><<<dim3(42, 16, 1), 256, 0, stream>>>(
        xmod, wTg + (size_t)l * HDIM * NODE_D, NODE_D, NODE_D, NODE_D, h, HDIM,
        b_gva + (size_t)l * HDIM, nullptr, 0, 0, 0, 0);

    qk_rope_kernel<<<2048, 256, 0, stream>>>(h, mhs_w + l * 2 * ATTN_D,
                                             mhs_b + l * 2 * ATTN_D, qk_sc,
                                             trig, q, kk);

    // V slice of h (per batch 1024 x 2560, ld=5376) -> Vt (2560 x 1024)
    transpose_int<<<dim3(40, 16, 2), 256, 0, stream>>>(
        h + PROJ_D, Vt, HDIM, LSEQ, (long)LSEQ * HDIM, (long)PROJ_D * LSEQ);

    // S = q@k^T + bias + rel  (per batch via grid.z)
    gemm_bt<1><<<dim3(8, 8, 2), 256, 0, stream>>>(
        q, kk, ATTN_D, ATTN_D, ATTN_D, S, LSEQ,
        bias, relpos + l * 129,
        (long)LSEQ * ATTN_D, (long)LSEQ * ATTN_D, (long)LSEQ * LSEQ * 4,
        (long)LSEQ * 4);

    softmax_kernel<<<2048, 256, 0, stream>>>(S, P);
    if (l == 3) edge_kernel<<<1024, 256, 0, stream>>>(P, outEdge);

    // po = (P @ V) * gates
    gemm_bt<2><<<dim3(20, 8, 2), 256, 0, stream>>>(
        P, Vt, LSEQ, LSEQ, LSEQ, po, PROJ_D,
        h, nullptr,
        (long)LSEQ * LSEQ, (long)PROJ_D * LSEQ, (long)LSEQ * PROJ_D * 2,
        (long)LSEQ * HDIM * 2);

    // split-K partials: Pp[z] = po[:, z*1280:(z+1)*1280] @ w_out-slice
    gemm_bt<4><<<dim3(10, 16, 2), 256, 0, stream>>>(
        po, wTo + (size_t)l * NODE_D * PROJ_D, 1280, PROJ_D, PROJ_D, Pp, NODE_D,
        nullptr, nullptr,
        1280, 1280, (long)NTOK * NODE_D * 4, 0);

    // node = resid + (p0+p1+b_out)*(1+alpha); produce next xmod / final out
    const float* resid = (l == 0) ? node_in : nodef;
    if (l < 3) {
      res_ln_fuse<false><<<2048, 256, 0, stream>>>(
          Pp, Pp + (size_t)NTOK * NODE_D, b_out + (size_t)l * NODE_D,
          gba + l * 2 * 3840, gba + (l + 1) * 2 * 3840, resid, nodef, xmod,
          nullptr);
    } else {
      res_ln_fuse<true><<<2048, 256, 0, stream>>>(
          Pp, Pp + (size_t)NTOK * NODE_D, b_out + (size_t)l * NODE_D,
          gba + l * 2 * 3840, nullptr, resid, nodef, nullptr, outNode);
    }
  }
}

// Round 6
// 788.824 us; speedup vs baseline: 1.0282x; 1.0282x over previous
//
#include <hip/hip_runtime.h>

// ---------------------------------------------------------------------------
// OmegaPLM block, MI355X (gfx950). Inputs AND output are FLOAT32.
// R7 (872us): split-K stores; res_ln_fuse; merged V-transpose.
// R9 (793us): GEMM BK=64 + both-sides XOR swizzle (u^=row&7 @16B units);
// RoPE trig table.
// R10 (811us, REGRESSION): transpose hoist + copy removal GOOD; XCD block
// swizzle BAD (~-25us: operands are L2/L3-resident, not HBM-bound regime;
// y-fastest remap also broke default A-row locality).
// R11: revert XCD swizzle (gemm_bt addressing = R9 exactly); keep hoist +
// copy removal; fuse qk_rope + V-transpose into one flat-grid dispatch
// (blocks 0-1279 transpose, 1280-3327 rope) — one fewer dispatch/layer.
// No arithmetic changes: output bit-identical to R9/R10.
// ---------------------------------------------------------------------------

typedef __bf16 bf16;
typedef __attribute__((ext_vector_type(8))) __bf16 bf16x8;
typedef __attribute__((ext_vector_type(4))) float f32x4;

#define NODE_D 1280
#define PROJ_D 2560
#define ATTN_D 256
#define HDIM 5376     // 2*PROJ + ATTN
#define LSEQ 1024
#define NTOK 2048     // B*L

__device__ __forceinline__ void async_ld16(const void* gsrc, void* ldst) {
  __builtin_amdgcn_global_load_lds(
      (__attribute__((address_space(1))) void*)gsrc,
      (__attribute__((address_space(3))) void*)ldst, 16, 0, 0);
}

__device__ __forceinline__ float sigmoidf_fast(float x) {
  return 1.f / (1.f + __expf(-x));
}

// ---------------------------------------------------------------------------
// GEMM: C[M,N] = A[M,K] * Bt[N,K]^T, bf16 inputs, fp32 accumulate.
// 128x128 tile, BK=64, 4 waves, 4x4 grid of 16x16x32 MFMAs per wave.
// LDS swizzle: physical unit = nominal unit ^ (row&7) (16B units), applied
// on the global source (global_load_lds writes linearly) AND the ds_read.
// MODE 0: h = silu(acc + b_gva_f32[col])                    -> bf16 C
// MODE 1: S = acc + bias_f32[col] + rel_f32[clip(row-col)]  -> f32 C
// MODE 2: po = acc * gates_bf16[row,col]                    -> bf16 C
// MODE 4: plain f32 partial store (split-K, reduced later)  -> f32 C
// ---------------------------------------------------------------------------
template <int MODE>
__global__ __launch_bounds__(256, 3) void gemm_bt(
    const bf16* __restrict__ A, const bf16* __restrict__ Bt, int K,
    int lda, int ldb, void* __restrict__ C, int ldc,
    const void* __restrict__ E0, const void* __restrict__ E1,
    long zA, long zB, long zCb, long zE0b) {
  __shared__ __align__(16) bf16 As[128 * 64];
  __shared__ __align__(16) bf16 Bs[128 * 64];

  const int z = blockIdx.z;
  A += (size_t)zA * z;
  Bt += (size_t)zB * z;
  char* Cb = (char*)C + (size_t)zCb * z;
  const char* e0 = (const char*)E0 + (size_t)zE0b * z;

  const int rowBase = blockIdx.y * 128;
  const int colBase = blockIdx.x * 128;
  const int tid = threadIdx.x;
  const int lane = tid & 63;
  const int wv = tid >> 6;
  const int wrow = (wv >> 1) * 64;
  const int wcol = (wv & 1) * 64;
  const int fm = lane & 15;
  const int fq = lane >> 4;

  const bf16* Ablk = A + (size_t)rowBase * lda;
  const bf16* Bblk = Bt + (size_t)colBase * ldb;

  f32x4 zero = {0.f, 0.f, 0.f, 0.f};
  f32x4 acc[4][4];
#pragma unroll
  for (int i = 0; i < 4; i++)
#pragma unroll
    for (int j = 0; j < 4; j++) acc[i][j] = zero;

  for (int k0 = 0; k0 < K; k0 += 64) {
    __syncthreads();
#pragma unroll
    for (int i = 0; i < 4; i++) {
      const int slot = tid + i * 256;          // this thread's 16B slot
      const int row = slot >> 3;               // tile-local row 0..127
      const int u = (slot & 7) ^ (row & 7);    // swizzled source unit
      bf16* dA = As + ((i * 256 + wv * 64) << 3);  // wave-uniform LDS base
      bf16* dB = Bs + ((i * 256 + wv * 64) << 3);
      async_ld16(Ablk + (size_t)row * lda + k0 + (u << 3), dA);
      async_ld16(Bblk + (size_t)row * ldb + k0 + (u << 3), dB);
    }
    __syncthreads();

#pragma unroll
    for (int s = 0; s < 2; s++) {
      bf16x8 aF[4], bF[4];
#pragma unroll
      for (int i = 0; i < 4; i++) {
        const int r = wrow + i * 16 + fm;
        aF[i] = *(const bf16x8*)(As + r * 64 +
                                 ((((s << 2) | fq) ^ (r & 7)) << 3));
      }
#pragma unroll
      for (int j = 0; j < 4; j++) {
        const int r = wcol + j * 16 + fm;
        bF[j] = *(const bf16x8*)(Bs + r * 64 +
                                 ((((s << 2) | fq) ^ (r & 7)) << 3));
      }
#pragma unroll
      for (int i = 0; i < 4; i++)
#pragma unroll
        for (int j = 0; j < 4; j++)
          acc[i][j] = __builtin_amdgcn_mfma_f32_16x16x32_bf16(
              aF[i], bF[j], acc[i][j], 0, 0, 0);
    }
  }

  // epilogue: C/D layout col=lane&15, row=quad*4+reg
#pragma unroll
  for (int i = 0; i < 4; i++) {
#pragma unroll
    for (int t = 0; t < 4; t++) {
      const int r = rowBase + wrow + i * 16 + fq * 4 + t;
#pragma unroll
      for (int j = 0; j < 4; j++) {
        const int cc = colBase + wcol + j * 16 + fm;
        float v = acc[i][j][t];
        if constexpr (MODE == 0) {
          v += ((const float*)e0)[cc];
          v = v * sigmoidf_fast(v);
          ((bf16*)Cb)[(size_t)r * ldc + cc] = (bf16)v;
        } else if constexpr (MODE == 1) {
          v += ((const float*)e0)[cc];
          int d = r - cc;
          d = d < -64 ? -64 : (d > 64 ? 64 : d);
          v += ((const float*)E1)[d + 64];
          ((float*)Cb)[(size_t)r * ldc + cc] = v;
        } else if constexpr (MODE == 2) {
          float gt = (float)((const bf16*)e0)[(size_t)r * HDIM + cc];
          ((bf16*)Cb)[(size_t)r * ldc + cc] = (bf16)(v * gt);
        } else {  // MODE 4: split-K partial, plain store
          ((float*)Cb)[(size_t)r * ldc + cc] = v;
        }
      }
    }
  }
}

// ---------------------------------------------------------------------------
// transpose f32 weight -> bf16: out[c][r] = (bf16)in[r][c]. 64x64 tiles.
// z-batched over layers via grid.z.
// ---------------------------------------------------------------------------
__global__ void transpose_f2b(const float* __restrict__ in0,
                              bf16* __restrict__ out0, int ldin, int ldout,
                              long zIn, long zOut) {
  __shared__ __align__(16) bf16 t[64][72];
  const float* in = in0 + (size_t)zIn * blockIdx.z;
  bf16* out = out0 + (size_t)zOut * blockIdx.z;
  const int rb = blockIdx.y * 64, cb = blockIdx.x * 64;
  const int tx = threadIdx.x & 7, ty = threadIdx.x >> 3;
#pragma unroll
  for (int rr = 0; rr < 64; rr += 32) {
    const int r = ty + rr;
    const float4* p = (const float4*)&in[(size_t)(rb + r) * ldin + cb + tx * 8];
    float4 a = p[0], b = p[1];
    t[tx * 8 + 0][r] = (bf16)a.x; t[tx * 8 + 1][r] = (bf16)a.y;
    t[tx * 8 + 2][r] = (bf16)a.z; t[tx * 8 + 3][r] = (bf16)a.w;
    t[tx * 8 + 4][r] = (bf16)b.x; t[tx * 8 + 5][r] = (bf16)b.y;
    t[tx * 8 + 6][r] = (bf16)b.z; t[tx * 8 + 7][r] = (bf16)b.w;
  }
  __syncthreads();
#pragma unroll
  for (int rr = 0; rr < 64; rr += 32) {
    const int c = ty + rr;
    *(bf16x8*)&out[(size_t)(cb + c) * ldout + rb + tx * 8] =
        *(const bf16x8*)&t[c][tx * 8];
  }
}

// ---------------------------------------------------------------------------
// Fused: V-transpose (blocks 0..1279) + qk rope (blocks 1280..3327).
// Transpose: V slice of h (per batch 1024x2560, ld=5376) -> Vt (2560x1024).
// Rope: q,k from h base slice, mhs modulate, trig table, fold qk_scaling.
// ---------------------------------------------------------------------------
__global__ void rope_vt_kernel(const bf16* __restrict__ h,
                               const float* __restrict__ mhs_w,
                               const float* __restrict__ mhs_b,
                               const float* __restrict__ qk_sc,
                               const float* __restrict__ trig,
                               bf16* __restrict__ q, bf16* __restrict__ k,
                               bf16* __restrict__ Vt) {
  __shared__ __align__(16) bf16 t[64][72];
  const int bid = blockIdx.x;
  if (bid < 1280) {
    // ---- V transpose tile ----
    const int z = bid >> 9 >= 1 && bid >= 640 ? 1 : 0;  // bid/640
    const int zz = bid / 640;
    const int rem = bid - zz * 640;
    const int bx = rem % 40, by = rem / 40;
    (void)z;
    const bf16* in = h + (size_t)zz * LSEQ * HDIM + PROJ_D;
    bf16* out = Vt + (size_t)zz * PROJ_D * LSEQ;
    const int rb = by * 64, cb = bx * 64;
    const int tx = threadIdx.x & 7, ty = threadIdx.x >> 3;
#pragma unroll
    for (int rr = 0; rr < 64; rr += 32) {
      const int r = ty + rr;
      bf16x8 v = *(const bf16x8*)&in[(size_t)(rb + r) * HDIM + cb + tx * 8];
#pragma unroll
      for (int e = 0; e < 8; e++) t[tx * 8 + e][r] = v[e];
    }
    __syncthreads();
#pragma unroll
    for (int rr = 0; rr < 64; rr += 32) {
      const int c = ty + rr;
      *(bf16x8*)&out[(size_t)(cb + c) * LSEQ + rb + tx * 8] =
          *(const bf16x8*)&t[c][tx * 8];
    }
  } else {
    // ---- rope for one token ----
    const int tok = bid - 1280;
    const int pos = tok & (LSEQ - 1);
    const int d = threadIdx.x;
    const bf16* base = h + (size_t)tok * HDIM + 2 * PROJ_D;
    const int j = d & 127;
    const float2 cssn = ((const float2*)trig)[pos * 128 + j];
    const float cs = cssn.x, sn = cssn.y;
    const float bd = (float)base[d];
    const int pd = (d < 128) ? d + 128 : d - 128;
    const float bp = (float)base[pd];
    const float sgn = (d < 128) ? -1.f : 1.f;

    float v = bd * mhs_w[d] + mhs_b[d];
    float vp = bp * mhs_w[pd] + mhs_b[pd];
    float r0 = v * cs + sgn * vp * sn;
    q[(size_t)tok * ATTN_D + d] = (bf16)(r0 * qk_sc[tok]);

    float v1 = bd * mhs_w[ATTN_D + d] + mhs_b[ATTN_D + d];
    float v1p = bp * mhs_w[ATTN_D + pd] + mhs_b[ATTN_D + pd];
    float r1 = v1 * cs + sgn * v1p * sn;
    k[(size_t)tok * ATTN_D + d] = (bf16)r1;
  }
}

// ---------------------------------------------------------------------------
// adaLN: gba[l][b][:] = silu(cond[b]) @ w_adaln[l] + b_adaln[l]
// ---------------------------------------------------------------------------
__global__ void gba_init(const float* __restrict__ b_adaln,
                         float* __restrict__ gba) {
  const int i = blockIdx.x * 256 + threadIdx.x;  // over 4*2*3840
  if (i < 4 * 2 * 3840) {
    const int l = i / (2 * 3840);
    const int c = i % 3840;
    gba[i] = b_adaln[l * 3840 + c];
  }
}

// grid (30, 4, 8), 256 thr = 128 cols x 2 k-subgroups; k chunk = 160 per z.
__global__ void adaln_part(const float* __restrict__ cond,
                           const float* __restrict__ w_adaln,
                           float* __restrict__ gba) {
  __shared__ float sc[2 * NODE_D];
  __shared__ float red[2][2][128];
  const int l = blockIdx.y, z = blockIdx.z;
  const int cl = threadIdx.x & 127;
  const int col = blockIdx.x * 128 + cl;
  const int kg = threadIdx.x >> 7;
  for (int i = threadIdx.x; i < 2 * NODE_D; i += 256) {
    float v = cond[i];
    sc[i] = v * sigmoidf_fast(v);
  }
  __syncthreads();
  const float* w = w_adaln + (size_t)l * NODE_D * 3840;
  const int k0 = z * 160 + kg * 80;
  float a0 = 0.f, a1 = 0.f;
  for (int k = k0; k < k0 + 80; k++) {
    float wv = w[(size_t)k * 3840 + col];
    a0 += sc[k] * wv;
    a1 += sc[NODE_D + k] * wv;
  }
  red[kg][0][cl] = a0;
  red[kg][1][cl] = a1;
  __syncthreads();
  if (kg == 0) {
    a0 += red[1][0][cl];
    a1 += red[1][1][cl];
    atomicAdd(&gba[(size_t)(l * 2 + 0) * 3840 + col], a0);
    atomicAdd(&gba[(size_t)(l * 2 + 1) * 3840 + col], a1);
  }
}

// xmod = LN(x) * (1+gamma) + beta, bf16 out. grid=2048, 256 thr. (layer 0)
__global__ void ln_mod_kernel(const float* __restrict__ xin,
                              const float* __restrict__ gba_l,
                              bf16* __restrict__ xmod) {
  __shared__ float red[2][4];
  const int row = blockIdx.x, b = row >> 10, tt = threadIdx.x;
  const float* x = xin + (size_t)row * NODE_D;
  float vals[5], s = 0.f, s2 = 0.f;
#pragma unroll
  for (int i = 0; i < 5; i++) {
    float v = x[tt + i * 256];
    vals[i] = v; s += v; s2 += v * v;
  }
#pragma unroll
  for (int off = 32; off >= 1; off >>= 1) {
    s += __shfl_down(s, off, 64);
    s2 += __shfl_down(s2, off, 64);
  }
  const int wv = tt >> 6, lane = tt & 63;
  if (lane == 0) { red[0][wv] = s; red[1][wv] = s2; }
  __syncthreads();
  s = red[0][0] + red[0][1] + red[0][2] + red[0][3];
  s2 = red[1][0] + red[1][1] + red[1][2] + red[1][3];
  const float mean = s * (1.f / NODE_D);
  const float var = s2 * (1.f / NODE_D) - mean * mean;
  const float inv = rsqrtf(var + 1e-5f);
  const float* gm = gba_l + b * 3840;
#pragma unroll
  for (int i = 0; i < 5; i++) {
    const int c = tt + i * 256;
    float v = (vals[i] - mean) * inv * (1.f + gm[c]) + gm[NODE_D + c];
    xmod[(size_t)row * NODE_D + c] = (bf16)v;
  }
}

// ---------------------------------------------------------------------------
// res_ln_fuse: node_new = resid + (p0+p1+b_out)*(1+alpha);
//   LAST=0: nodef <- node_new; xmod <- LN(node_new)*(1+gamma_next)+beta_next
//   LAST=1: outNode <- node_new (no LN needed)
// resid = node_in for layer 0, nodef otherwise. grid=2048, 256 thr x 5.
// ---------------------------------------------------------------------------
template <bool LAST>
__global__ void res_ln_fuse(const float* __restrict__ p0,
                            const float* __restrict__ p1,
                            const float* __restrict__ b_out_l,
                            const float* __restrict__ gba_l,     // alpha at +2560
                            const float* __restrict__ gba_next,  // gamma/beta
                            const float* __restrict__ resid,
                            float* __restrict__ nodef,
                            bf16* __restrict__ xmod,
                            float* __restrict__ outNode) {
  __shared__ float red[2][4];
  const int row = blockIdx.x, b = row >> 10, tt = threadIdx.x;
  const float* a0 = p0 + (size_t)row * NODE_D;
  const float* a1 = p1 + (size_t)row * NODE_D;
  const float* rs = resid + (size_t)row * NODE_D;
  const float* al = gba_l + b * 3840 + 2560;
  float vals[5], s = 0.f, s2 = 0.f;
#pragma unroll
  for (int i = 0; i < 5; i++) {
    const int c = tt + i * 256;
    float delta = (a0[c] + a1[c] + b_out_l[c]) * (1.f + al[c]);
    float v = rs[c] + delta;
    if (LAST) {
      outNode[(size_t)row * NODE_D + c] = v;
    } else {
      nodef[(size_t)row * NODE_D + c] = v;
    }
    vals[i] = v; s += v; s2 += v * v;
  }
  if (!LAST) {
#pragma unroll
    for (int off = 32; off >= 1; off >>= 1) {
      s += __shfl_down(s, off, 64);
      s2 += __shfl_down(s2, off, 64);
    }
    const int wv = tt >> 6, lane = tt & 63;
    if (lane == 0) { red[0][wv] = s; red[1][wv] = s2; }
    __syncthreads();
    s = red[0][0] + red[0][1] + red[0][2] + red[0][3];
    s2 = red[1][0] + red[1][1] + red[1][2] + red[1][3];
    const float mean = s * (1.f / NODE_D);
    const float var = s2 * (1.f / NODE_D) - mean * mean;
    const float inv = rsqrtf(var + 1e-5f);
    const float* gm = gba_next + b * 3840;
#pragma unroll
    for (int i = 0; i < 5; i++) {
      const int c = tt + i * 256;
      float v = (vals[i] - mean) * inv * (1.f + gm[c]) + gm[NODE_D + c];
      xmod[(size_t)row * NODE_D + c] = (bf16)v;
    }
  }
}

// precompute RoPE table: tab[pos][j] = (cos, sin)(pos * 10000^(-j/128))
__global__ void trig_init(float* __restrict__ tab) {
  const int pos = blockIdx.x;   // 1024
  const int j = threadIdx.x;    // 128
  const float freq = __expf(-(float)j * 0.07195578415606392f);
  const float ang = (float)pos * freq;
  tab[(pos * 128 + j) * 2 + 0] = cosf(ang);
  tab[(pos * 128 + j) * 2 + 1] = sinf(ang);
}

// row softmax: S (f32, 1024 cols) -> P (bf16). grid=2048, 256 thr x 4 elems.
__global__ void softmax_kernel(const float* __restrict__ S, bf16* __restrict__ P) {
  __shared__ float red[8];
  const size_t row = blockIdx.x;
  const float* s = S + row * LSEQ;
  const int tt = threadIdx.x, wv = tt >> 6, lane = tt & 63;
  float v[4];
  float m = -1e30f;
#pragma unroll
  for (int i = 0; i < 4; i++) {
    v[i] = s[tt + i * 256];
    m = fmaxf(m, v[i]);
  }
#pragma unroll
  for (int off = 32; off >= 1; off >>= 1) m = fmaxf(m, __shfl_down(m, off, 64));
  if (lane == 0) red[wv] = m;
  __syncthreads();
  m = fmaxf(fmaxf(red[0], red[1]), fmaxf(red[2], red[3]));
  float sum = 0.f;
#pragma unroll
  for (int i = 0; i < 4; i++) {
    v[i] = __expf(v[i] - m);
    sum += v[i];
  }
#pragma unroll
  for (int off = 32; off >= 1; off >>= 1) sum += __shfl_down(sum, off, 64);
  __syncthreads();
  if (lane == 0) red[4 + wv] = sum;
  __syncthreads();
  const float inv = 1.f / (red[4] + red[5] + red[6] + red[7]);
  bf16* p = P + row * LSEQ;
#pragma unroll
  for (int i = 0; i < 4; i++) p[tt + i * 256] = (bf16)(v[i] * inv);
}

// edge = sum over batch of attn (last layer), f32 out
__global__ void edge_kernel(const bf16* __restrict__ P, float* __restrict__ out) {
  const int idx = (blockIdx.x * 256 + threadIdx.x) * 4;
#pragma unroll
  for (int i = 0; i < 4; i++)
    out[idx + i] = (float)P[idx + i] + (float)P[1048576 + idx + i];
}

// ---------------------------------------------------------------------------
extern "C" void kernel_launch(void* const* d_in, const int* in_sizes, int n_in,
                              void* d_out, int out_size, void* d_ws, size_t ws_size,
                              hipStream_t stream) {
  const float* node_in = (const float*)d_in[0];
  const float* qk_sc   = (const float*)d_in[1];
  const float* bias    = (const float*)d_in[2];
  const float* cond    = (const float*)d_in[3];
  const float* w_gva   = (const float*)d_in[4];
  const float* b_gva   = (const float*)d_in[5];
  const float* mhs_w   = (const float*)d_in[6];
  const float* mhs_b   = (const float*)d_in[7];
  const float* relpos  = (const float*)d_in[8];
  const float* w_out   = (const float*)d_in[9];
  const float* b_out   = (const float*)d_in[10];
  const float* w_adaln = (const float*)d_in[11];
  const float* b_adaln = (const float*)d_in[12];
  (void)in_sizes; (void)n_in; (void)out_size; (void)ws_size;

  char* wsp = (char*)d_ws;
  auto alloc = [&](size_t bytes) {
    char* p = wsp;
    wsp += (bytes + 255) & ~(size_t)255;
    return p;
  };
  float* nodef = (float*)alloc((size_t)NTOK * NODE_D * 4);   // fp32 residual
  float* gba   = (float*)alloc((size_t)8 * 3840 * 4);
  bf16* xmod   = (bf16*)alloc((size_t)NTOK * NODE_D * 2);
  bf16* h      = (bf16*)alloc((size_t)NTOK * HDIM * 2);
  bf16* q      = (bf16*)alloc((size_t)NTOK * ATTN_D * 2);
  bf16* kk     = (bf16*)alloc((size_t)NTOK * ATTN_D * 2);
  bf16* Vt     = (bf16*)alloc((size_t)2 * PROJ_D * LSEQ * 2);
  bf16* wTg    = (bf16*)alloc((size_t)4 * HDIM * NODE_D * 2);   // GVA weights^T
  bf16* wTo    = (bf16*)alloc((size_t)4 * NODE_D * PROJ_D * 2); // OUT weights^T
  float* S     = (float*)alloc((size_t)2 * LSEQ * LSEQ * 4);
  bf16* P      = (bf16*)alloc((size_t)2 * LSEQ * LSEQ * 2);
  bf16* po     = (bf16*)alloc((size_t)NTOK * PROJ_D * 2);
  float* Pp    = (float*)alloc((size_t)2 * NTOK * NODE_D * 4);  // split-K partials
  float* trig  = (float*)alloc((size_t)LSEQ * 128 * 2 * 4);     // RoPE table

  float* outNode = (float*)d_out;
  float* outEdge = outNode + (size_t)NTOK * NODE_D;

  // ---- preamble: tables, adaLN, layer-0 LN, all weight transposes ----
  trig_init<<<1024, 128, 0, stream>>>(trig);
  gba_init<<<120, 256, 0, stream>>>(b_adaln, gba);
  adaln_part<<<dim3(30, 4, 8), 256, 0, stream>>>(cond, w_adaln, gba);
  ln_mod_kernel<<<2048, 256, 0, stream>>>(node_in, gba, xmod);
  // w_gva (4 x 1280 x 5376 f32) -> wTg (4 x 5376 x 1280 bf16)
  transpose_f2b<<<dim3(84, 20, 4), 256, 0, stream>>>(
      w_gva, wTg, HDIM, NODE_D, (long)NODE_D * HDIM, (long)HDIM * NODE_D);
  // w_out (4 x 2560 x 1280 f32) -> wTo (4 x 1280 x 2560 bf16)
  transpose_f2b<<<dim3(20, 40, 4), 256, 0, stream>>>(
      w_out, wTo, NODE_D, PROJ_D, (long)PROJ_D * NODE_D, (long)NODE_D * PROJ_D);

  for (int l = 0; l < 4; ++l) {
    // h = silu(xmod @ w_gva + b_gva)
    gemm_bt<0><<<dim3(42, 16, 1), 256, 0, stream>>>(
        xmod, wTg + (size_t)l * HDIM * NODE_D, NODE_D, NODE_D, NODE_D, h, HDIM,
        b_gva + (size_t)l * HDIM, nullptr, 0, 0, 0, 0);

    // fused: V-transpose (1280 blocks) + qk rope (2048 blocks)
    rope_vt_kernel<<<3328, 256, 0, stream>>>(h, mhs_w + l * 2 * ATTN_D,
                                             mhs_b + l * 2 * ATTN_D, qk_sc,
                                             trig, q, kk, Vt);

    // S = q@k^T + bias + rel  (per batch via grid.z)
    gemm_bt<1><<<dim3(8, 8, 2), 256, 0, stream>>>(
        q, kk, ATTN_D, ATTN_D, ATTN_D, S, LSEQ,
        bias, relpos + l * 129,
        (long)LSEQ * ATTN_D, (long)LSEQ * ATTN_D, (long)LSEQ * LSEQ * 4,
        (long)LSEQ * 4);

    softmax_kernel<<<2048, 256, 0, stream>>>(S, P);
    if (l == 3) edge_kernel<<<1024, 256, 0, stream>>>(P, outEdge);

    // po = (P @ V) * gates
    gemm_bt<2><<<dim3(20, 8, 2), 256, 0, stream>>>(
        P, Vt, LSEQ, LSEQ, LSEQ, po, PROJ_D,
        h, nullptr,
        (long)LSEQ * LSEQ, (long)PROJ_D * LSEQ, (long)LSEQ * PROJ_D * 2,
        (long)LSEQ * HDIM * 2);

    // split-K partials: Pp[z] = po[:, z*1280:(z+1)*1280] @ w_out-slice
    gemm_bt<4><<<dim3(10, 16, 2), 256, 0, stream>>>(
        po, wTo + (size_t)l * NODE_D * PROJ_D, 1280, PROJ_D, PROJ_D, Pp, NODE_D,
        nullptr, nullptr,
        1280, 1280, (long)NTOK * NODE_D * 4, 0);

    // node = resid + (p0+p1+b_out)*(1+alpha); produce next xmod / final out
    const float* resid = (l == 0) ? node_in : nodef;
    if (l < 3) {
      res_ln_fuse<false><<<2048, 256, 0, stream>>>(
          Pp, Pp + (size_t)NTOK * NODE_D, b_out + (size_t)l * NODE_D,
          gba + l * 2 * 3840, gba + (l + 1) * 2 * 3840, resid, nodef, xmod,
          nullptr);
    } else {
      res_ln_fuse<true><<<2048, 256, 0, stream>>>(
          Pp, Pp + (size_t)NTOK * NODE_D, b_out + (size_t)l * NODE_D,
          gba + l * 2 * 3840, nullptr, resid, nodef, nullptr, outNode);
    }
  }
}